// Round 1
// baseline (362.790 us; speedup 1.0000x reference)
//
#include <hip/hip_runtime.h>
#include <math.h>

#define SEQ    2048
#define DIMM   512
#define SH     128
#define EXP    1024
#define PROJ_  2176
#define NBATCH 8
#define ROWS   16384  // NBATCH*SEQ

typedef __attribute__((ext_vector_type(8))) short   short8;
typedef __attribute__((ext_vector_type(4))) float   floatx4;

__device__ __forceinline__ unsigned short f2bf(float f) {
  union { float f; unsigned int u; } v; v.f = f;
  unsigned int r = (v.u + 0x7fffu + ((v.u >> 16) & 1u)) >> 16;
  return (unsigned short)r;
}
__device__ __forceinline__ float bf2f(unsigned short h) {
  union { unsigned int u; float f; } v; v.u = ((unsigned int)h) << 16;
  return v.f;
}

__device__ __forceinline__ void async16(const unsigned short* g, unsigned short* l) {
  __builtin_amdgcn_global_load_lds(
      (const __attribute__((address_space(1))) void*)g,
      (__attribute__((address_space(3))) void*)l, 16, 0, 0);
}

// ---------------- RMSNorm: x (fp32, row=512) -> xn (bf16) ----------------
struct __align__(8) US4 { unsigned short a, b, c, d; };

__global__ void rmsnorm_kernel(const float* __restrict__ x, const float* __restrict__ ns,
                               unsigned short* __restrict__ xn) {
  int wave = threadIdx.x >> 6, lane = threadIdx.x & 63;
  long row = (long)blockIdx.x * 4 + wave;
  const float4* xr = (const float4*)(x + row * DIMM);
  float4 v0 = xr[lane], v1 = xr[lane + 64];
  float ss = v0.x*v0.x + v0.y*v0.y + v0.z*v0.z + v0.w*v0.w
           + v1.x*v1.x + v1.y*v1.y + v1.z*v1.z + v1.w*v1.w;
  #pragma unroll
  for (int o = 32; o > 0; o >>= 1) ss += __shfl_xor(ss, o);
  float sc = rsqrtf(ss * (1.0f / DIMM) + 1e-6f) * ns[0];
  US4 w0 = { f2bf(v0.x*sc), f2bf(v0.y*sc), f2bf(v0.z*sc), f2bf(v0.w*sc) };
  US4 w1 = { f2bf(v1.x*sc), f2bf(v1.y*sc), f2bf(v1.z*sc), f2bf(v1.w*sc) };
  ((US4*)(xn + row * DIMM))[lane]      = w0;
  ((US4*)(xn + row * DIMM))[lane + 64] = w1;
}

// ------------- transpose + fp32->bf16: in (R x C) -> out (C x R) -------------
__global__ void transpose_cvt(const float* __restrict__ in, unsigned short* __restrict__ out,
                              int R, int C) {
  __shared__ float tile[32][33];
  int c0 = blockIdx.x * 32, r0 = blockIdx.y * 32;
  #pragma unroll
  for (int j = 0; j < 32; j += 8)
    tile[threadIdx.y + j][threadIdx.x] = in[(long)(r0 + threadIdx.y + j) * C + c0 + threadIdx.x];
  __syncthreads();
  #pragma unroll
  for (int j = 0; j < 32; j += 8)
    out[(long)(c0 + threadIdx.y + j) * R + r0 + threadIdx.x] = f2bf(tile[threadIdx.x][threadIdx.y + j]);
}

// ------------- Toeplitz RoPE table: t(d), d = n - m in [-2047, 2047] -------------
__global__ void toeplitz_kernel(const float* __restrict__ a, const float* __restrict__ b,
                                float* __restrict__ tpl) {
  const int d = (int)blockIdx.x - 2047;
  const int tid = threadIdx.x;
  float sum = 0.0f;
  for (int k = tid; k < 1024; k += 256) {
    float a1 = a[k], a2 = a[k + 1024];
    float b1v = b[k], b2v = b[k + 1024];
    float p = a1 * b1v + a2 * b2v;
    float q = a1 * b2v - a2 * b1v;
    float th = powf(10000.0f, -(float)k * (1.0f / 1024.0f));
    float ang = (float)d * th;
    sum += p * cosf(ang) + q * sinf(ang);
  }
  #pragma unroll
  for (int o = 32; o > 0; o >>= 1) sum += __shfl_xor(sum, o);
  __shared__ float red[4];
  int wave = tid >> 6, lane = tid & 63;
  if (lane == 0) red[wave] = sum;
  __syncthreads();
  if (tid == 0) tpl[blockIdx.x] = red[0] + red[1] + red[2] + red[3];
}

// ------------- shared MFMA core: C(128x128) = A(rowBase..,K) . B(colBase..,K)^T -------------
// A, B row-major bf16 with leading dim K (K % 64 == 0). XOR-swizzled LDS granules.
__device__ __forceinline__ void mfma_core(const unsigned short* __restrict__ A,
                                          const unsigned short* __restrict__ B,
                                          int K, long rowBase, long colBase,
                                          unsigned short* smem, floatx4 acc[4][4]) {
  unsigned short* As = smem;
  unsigned short* Bs = smem + 128 * 64;
  const int tid  = threadIdx.x;
  const int wave = tid >> 6;
  const int lane = tid & 63;
  const int wr   = (wave >> 1) * 64;
  const int wc   = (wave & 1) * 64;
  const int r_l  = lane >> 3;   // staging row within 8-row group
  const int c8   = lane & 7;    // staging granule (8 bf16)
  const int fm   = lane & 15;   // fragment row
  const int fq   = lane >> 4;   // fragment quad

  floatx4 z = {0.0f, 0.0f, 0.0f, 0.0f};
  #pragma unroll
  for (int mi = 0; mi < 4; ++mi)
    #pragma unroll
    for (int ni = 0; ni < 4; ++ni) acc[mi][ni] = z;

  for (int k0 = 0; k0 < K; k0 += 64) {
    __syncthreads();
    #pragma unroll
    for (int j = 0; j < 4; ++j) {
      int row = j * 32 + wave * 8 + r_l;
      int g = c8 ^ (row & 7);  // swizzle: LDS granule c8 of row holds global granule g
      async16(A + (rowBase + row) * (long)K + k0 + g * 8, As + (j * 32 + wave * 8) * 64);
      async16(B + (colBase + row) * (long)K + k0 + g * 8, Bs + (j * 32 + wave * 8) * 64);
    }
    __syncthreads();  // drains vmcnt: global_load_lds complete
    #pragma unroll
    for (int ks = 0; ks < 2; ++ks) {
      short8 af[4], bfr[4];
      #pragma unroll
      for (int mi = 0; mi < 4; ++mi) {
        int row = wr + mi * 16 + fm;
        int gL = (ks * 4 + fq) ^ (row & 7);
        af[mi] = *(const short8*)(As + row * 64 + gL * 8);
      }
      #pragma unroll
      for (int ni = 0; ni < 4; ++ni) {
        int row = wc + ni * 16 + fm;
        int gL = (ks * 4 + fq) ^ (row & 7);
        bfr[ni] = *(const short8*)(Bs + row * 64 + gL * 8);
      }
      #pragma unroll
      for (int mi = 0; mi < 4; ++mi)
        #pragma unroll
        for (int ni = 0; ni < 4; ++ni)
          acc[mi][ni] = __builtin_amdgcn_mfma_f32_16x16x32_bf16(af[mi], bfr[ni], acc[mi][ni], 0, 0, 0);
    }
  }
}

#define EPILOGUE_VARS                                        \
  const int lane = threadIdx.x & 63, wave = threadIdx.x >> 6; \
  const int wr = (wave >> 1) * 64, wc = (wave & 1) * 64;      \
  const int fr = (lane >> 4) * 4, fc = lane & 15;

// ------------- GEMM1: uv = swish(xn @ W1 + b1); split into u, vT, q, k -------------
__global__ void gemm_uv(const unsigned short* __restrict__ xn,
                        const unsigned short* __restrict__ w1t,
                        const float* __restrict__ b1,
                        const float* __restrict__ gamma,
                        const float* __restrict__ beta,
                        unsigned short* __restrict__ u,
                        unsigned short* __restrict__ vT,
                        unsigned short* __restrict__ qb,
                        unsigned short* __restrict__ kb) {
  __shared__ __align__(16) unsigned short smem[2 * 128 * 64];
  floatx4 acc[4][4];
  long rowBase = (long)blockIdx.x * 128;
  long colBase = (long)blockIdx.y * 128;
  mfma_core(xn, w1t, DIMM, rowBase, colBase, smem, acc);
  EPILOGUE_VARS
  #pragma unroll
  for (int mi = 0; mi < 4; ++mi)
  #pragma unroll
  for (int ni = 0; ni < 4; ++ni)
  #pragma unroll
  for (int i = 0; i < 4; ++i) {
    long row = rowBase + wr + mi * 16 + fr + i;
    long col = colBase + wc + ni * 16 + fc;
    float t = acc[mi][ni][i] + b1[col];
    float s = t / (1.0f + __expf(-t));  // swish
    if (col < EXP) {
      u[row * EXP + col] = f2bf(s);
    } else if (col < 2 * EXP) {
      long b = row >> 11, n = row & 2047;
      vT[(b * EXP + (col - EXP)) * SEQ + n] = f2bf(s);
    } else {
      int dd = (int)(col - 2 * EXP);
      qb[row * SH + dd] = f2bf(s * gamma[dd] + beta[dd]);
      kb[row * SH + dd] = f2bf(s * gamma[SH + dd] + beta[SH + dd]);
    }
  }
}

// ------------- QK: ker = relu(q.k^T/2048 + t(n-m))^2, per batch -------------
__global__ void gemm_qk(const unsigned short* __restrict__ qb,
                        const unsigned short* __restrict__ kb,
                        const float* __restrict__ tpl,
                        unsigned short* __restrict__ ker) {
  __shared__ __align__(16) unsigned short smem[2 * 128 * 64];
  floatx4 acc[4][4];
  long b = blockIdx.z;
  long rowBase = (long)blockIdx.x * 128;
  long colBase = (long)blockIdx.y * 128;
  mfma_core(qb + b * SEQ * SH, kb + b * SEQ * SH, SH, rowBase, colBase, smem, acc);
  unsigned short* kerb = ker + b * SEQ * SEQ;
  EPILOGUE_VARS
  #pragma unroll
  for (int mi = 0; mi < 4; ++mi)
  #pragma unroll
  for (int ni = 0; ni < 4; ++ni)
  #pragma unroll
  for (int i = 0; i < 4; ++i) {
    long row = rowBase + wr + mi * 16 + fr + i;   // n
    long col = colBase + wc + ni * 16 + fc;       // m
    float val = acc[mi][ni][i] * (1.0f / 2048.0f) + tpl[row - col + 2047];
    float r = fmaxf(val, 0.0f);
    kerb[row * SEQ + col] = f2bf(r * r);
  }
}

// ------------- PV: o = (ker @ v) * u, per batch (v pre-transposed) -------------
__global__ void gemm_pv(const unsigned short* __restrict__ ker,
                        const unsigned short* __restrict__ vT,
                        const unsigned short* __restrict__ u,
                        unsigned short* __restrict__ ob) {
  __shared__ __align__(16) unsigned short smem[2 * 128 * 64];
  floatx4 acc[4][4];
  long b = blockIdx.z;
  long rowBase = (long)blockIdx.x * 128;
  long colBase = (long)blockIdx.y * 128;
  mfma_core(ker + b * SEQ * SEQ, vT + b * EXP * SEQ, SEQ, rowBase, colBase, smem, acc);
  const unsigned short* ub = u + b * SEQ * EXP;
  unsigned short* obb = ob + b * SEQ * EXP;
  EPILOGUE_VARS
  #pragma unroll
  for (int mi = 0; mi < 4; ++mi)
  #pragma unroll
  for (int ni = 0; ni < 4; ++ni)
  #pragma unroll
  for (int i = 0; i < 4; ++i) {
    long row = rowBase + wr + mi * 16 + fr + i;   // n (within batch)
    long col = colBase + wc + ni * 16 + fc;       // e
    float val = acc[mi][ni][i] * bf2f(ub[row * EXP + col]);
    obb[row * EXP + col] = f2bf(val);
  }
}

// ------------- OUT: out = o @ W2 + b2 + x -------------
__global__ void gemm_out(const unsigned short* __restrict__ ob,
                         const unsigned short* __restrict__ w2t,
                         const float* __restrict__ b2,
                         const float* __restrict__ x,
                         float* __restrict__ out) {
  __shared__ __align__(16) unsigned short smem[2 * 128 * 64];
  floatx4 acc[4][4];
  long rowBase = (long)blockIdx.x * 128;
  long colBase = (long)blockIdx.y * 128;
  mfma_core(ob, w2t, EXP, rowBase, colBase, smem, acc);
  EPILOGUE_VARS
  #pragma unroll
  for (int mi = 0; mi < 4; ++mi)
  #pragma unroll
  for (int ni = 0; ni < 4; ++ni)
  #pragma unroll
  for (int i = 0; i < 4; ++i) {
    long row = rowBase + wr + mi * 16 + fr + i;
    long col = colBase + wc + ni * 16 + fc;
    out[row * DIMM + col] = acc[mi][ni][i] + b2[col] + x[row * DIMM + col];
  }
}

extern "C" void kernel_launch(void* const* d_in, const int* in_sizes, int n_in,
                              void* d_out, int out_size, void* d_ws, size_t ws_size,
                              hipStream_t stream) {
  const float* x          = (const float*)d_in[0];
  const float* W1         = (const float*)d_in[1];
  const float* b1         = (const float*)d_in[2];
  const float* W2         = (const float*)d_in[3];
  const float* b2         = (const float*)d_in[4];
  const float* rope_a     = (const float*)d_in[5];
  const float* rope_b     = (const float*)d_in[6];
  const float* gamma      = (const float*)d_in[7];
  const float* beta       = (const float*)d_in[8];
  const float* norm_scale = (const float*)d_in[9];
  float* out = (float*)d_out;

  char* ws = (char*)d_ws;
  size_t off = 0;
  auto nxt = [&](size_t bytes) -> void* {
    void* p = ws + off;
    off += (bytes + 255) & ~(size_t)255;
    return p;
  };
  unsigned short* xn  = (unsigned short*)nxt((size_t)ROWS * DIMM * 2);
  unsigned short* w1t = (unsigned short*)nxt((size_t)PROJ_ * DIMM * 2);
  unsigned short* w2t = (unsigned short*)nxt((size_t)DIMM * EXP * 2);
  unsigned short* u   = (unsigned short*)nxt((size_t)ROWS * EXP * 2);
  unsigned short* vT  = (unsigned short*)nxt((size_t)NBATCH * EXP * SEQ * 2);
  unsigned short* qb  = (unsigned short*)nxt((size_t)ROWS * SH * 2);
  unsigned short* kb  = (unsigned short*)nxt((size_t)ROWS * SH * 2);
  float*          tpl = (float*)nxt((size_t)4096 * 4);
  unsigned short* ker = (unsigned short*)nxt((size_t)NBATCH * SEQ * SEQ * 2);
  unsigned short* ob  = (unsigned short*)nxt((size_t)ROWS * EXP * 2);

  rmsnorm_kernel<<<ROWS / 4, 256, 0, stream>>>(x, norm_scale, xn);
  transpose_cvt<<<dim3(PROJ_ / 32, DIMM / 32), dim3(32, 8), 0, stream>>>(W1, w1t, DIMM, PROJ_);
  transpose_cvt<<<dim3(DIMM / 32, EXP / 32), dim3(32, 8), 0, stream>>>(W2, w2t, EXP, DIMM);
  toeplitz_kernel<<<4095, 256, 0, stream>>>(rope_a, rope_b, tpl);
  gemm_uv<<<dim3(ROWS / 128, PROJ_ / 128), 256, 0, stream>>>(xn, w1t, b1, gamma, beta, u, vT, qb, kb);
  gemm_qk<<<dim3(SEQ / 128, SEQ / 128, NBATCH), 256, 0, stream>>>(qb, kb, tpl, ker);
  gemm_pv<<<dim3(SEQ / 128, EXP / 128, NBATCH), 256, 0, stream>>>(ker, vT, u, ob);
  gemm_out<<<dim3(ROWS / 128, DIMM / 128), 256, 0, stream>>>(ob, w2t, b2, x, out);
}